// Round 9
// baseline (21.293 us; speedup 1.0000x reference)
//
#include <hip/hip_runtime.h>
#include <float.h>

#define B_TOK 256
#define N_OUT 512
#define K_IN  1024

#define KSPLIT 8
#define KT     128   // k per block
#define BT     32    // b per block
#define NT     64    // n per block

// ---------------- Stage 1 ----------------
// grid (kc=8, ng=8, bg=8) = 512 blocks (2/CU); kc fastest -> kc = XCD (mod 8
// round-robin heuristic): per-XCD unique input slice ~0.4MB -> L2-resident.
// Block 256 thr = 4 waves. LDS 48KB: ws[64n][128k] + xs[32b][128k], swizzled.
// Wave wv owns k-chunks [8wv,8wv+8); lane (bq=ln>>3, nq=ln&7) owns a 4b x 8n
// register tile. Per 4k-chunk: 8 w-reads + 4 x-reads (b128) -> 128 products.
// 4-wave k-merge via LDS blob tree, wave 0 writes the kc partial plane.
__global__ __launch_bounds__(256)
void mam_stage1(const float* __restrict__ x, const float* __restrict__ w,
                float* __restrict__ pmx, float* __restrict__ pmn) {
    __shared__ float lds[12288];   // 48 KB: ws @0 (8192 f), xs @8192 (4096 f)
    float* ws = lds;
    float* xs = lds + 8192;

    const int tid = threadIdx.x;
    const int wv  = tid >> 6;
    const int ln  = tid & 63;
    const int kc  = blockIdx.x;
    const int n0  = blockIdx.y * NT;
    const int b0  = blockIdx.z * BT;
    const int k0  = kc * KT;

    // ---- stage w[n0..+63][k0..+127]: slot = c ^ ((r>>3)&7) ----
    // lanes -> 2 rows x 32 consecutive chunks per instr: coalesced 2x512B.
#pragma unroll
    for (int i = 0; i < 8; ++i) {
        const int s = tid + 256 * i;
        const int r = s >> 5, c = s & 31;
        const float4 v = *reinterpret_cast<const float4*>(
            w + (size_t)(n0 + r) * K_IN + k0 + 4 * c);
        *reinterpret_cast<float4*>(&ws[r * 128 + ((c ^ ((r >> 3) & 7)) << 2)]) = v;
    }
    // ---- stage x[b0..+31][k0..+127]: slot = c ^ ((r>>2)&7) ----
#pragma unroll
    for (int i = 0; i < 4; ++i) {
        const int s = tid + 256 * i;
        const int r = s >> 5, c = s & 31;
        const float4 v = *reinterpret_cast<const float4*>(
            x + (size_t)(b0 + r) * K_IN + k0 + 4 * c);
        *reinterpret_cast<float4*>(&xs[r * 128 + ((c ^ ((r >> 2) & 7)) << 2)]) = v;
    }
    __syncthreads();

    const int nq = ln & 7;    // n-oct: n = nq*8 + j
    const int bq = ln >> 3;   // b-quad: b = bq*4 + i

    float mx[4][8], mn[4][8];
#pragma unroll
    for (int i = 0; i < 4; ++i)
#pragma unroll
        for (int j = 0; j < 8; ++j) { mx[i][j] = -FLT_MAX; mn[i][j] = FLT_MAX; }

#pragma unroll 2
    for (int ci = 0; ci < 8; ++ci) {
        const int c = 8 * wv + ci;
        float4 wf[8], xf[4];
#pragma unroll
        for (int j = 0; j < 8; ++j)   // broadcast x8 across bq; 8 distinct slots: conflict-free
            wf[j] = *reinterpret_cast<const float4*>(
                &ws[(nq * 8 + j) * 128 + ((c ^ nq) << 2)]);
#pragma unroll
        for (int i = 0; i < 4; ++i)   // broadcast x8 across nq; 8 distinct slots
            xf[i] = *reinterpret_cast<const float4*>(
                &xs[(bq * 4 + i) * 128 + ((c ^ bq) << 2)]);

#pragma unroll
        for (int i = 0; i < 4; ++i) {
#pragma unroll
            for (int j = 0; j < 8; ++j) {
                const float p0 = xf[i].x * wf[j].x;
                const float p1 = xf[i].y * wf[j].y;
                const float p2 = xf[i].z * wf[j].z;
                const float p3 = xf[i].w * wf[j].w;
                mx[i][j] = fmaxf(fmaxf(mx[i][j], p0), p1);   // v_max3
                mx[i][j] = fmaxf(fmaxf(mx[i][j], p2), p3);
                mn[i][j] = fminf(fminf(mn[i][j], p0), p1);   // v_min3
                mn[i][j] = fminf(fminf(mn[i][j], p2), p3);
            }
        }
    }
    __syncthreads();   // all ws/xs reads done before blob reuse

    // ---- 4-wave k-merge: blobs of 16 float4/lane, layout [f][ln] (consecutive
    // 16B per lane per instr: standard conflict-free). buf0 @0, buf1 @4096. ----
#define BLOB_ST(BUF, F, V) \
    *reinterpret_cast<float4*>(&(BUF)[((F) * 64 + ln) * 4]) = (V)
#define BLOB_LD(BUF, F) \
    (*reinterpret_cast<const float4*>(&(BUF)[((F) * 64 + ln) * 4]))
#define WRITE_BLOB(BUF) do {                                                      \
    _Pragma("unroll")                                                             \
    for (int i = 0; i < 4; ++i) {                                                 \
        BLOB_ST(BUF, i * 2 + 0, make_float4(mx[i][0], mx[i][1], mx[i][2], mx[i][3])); \
        BLOB_ST(BUF, i * 2 + 1, make_float4(mx[i][4], mx[i][5], mx[i][6], mx[i][7])); \
        BLOB_ST(BUF, 8 + i * 2 + 0, make_float4(mn[i][0], mn[i][1], mn[i][2], mn[i][3])); \
        BLOB_ST(BUF, 8 + i * 2 + 1, make_float4(mn[i][4], mn[i][5], mn[i][6], mn[i][7])); \
    } } while (0)
#define MERGE_BLOB(BUF) do {                                                      \
    _Pragma("unroll")                                                             \
    for (int i = 0; i < 4; ++i) {                                                 \
        float4 a0 = BLOB_LD(BUF, i * 2 + 0), a1 = BLOB_LD(BUF, i * 2 + 1);        \
        float4 d0 = BLOB_LD(BUF, 8 + i * 2 + 0), d1 = BLOB_LD(BUF, 8 + i * 2 + 1);\
        mx[i][0] = fmaxf(mx[i][0], a0.x); mx[i][1] = fmaxf(mx[i][1], a0.y);       \
        mx[i][2] = fmaxf(mx[i][2], a0.z); mx[i][3] = fmaxf(mx[i][3], a0.w);       \
        mx[i][4] = fmaxf(mx[i][4], a1.x); mx[i][5] = fmaxf(mx[i][5], a1.y);       \
        mx[i][6] = fmaxf(mx[i][6], a1.z); mx[i][7] = fmaxf(mx[i][7], a1.w);       \
        mn[i][0] = fminf(mn[i][0], d0.x); mn[i][1] = fminf(mn[i][1], d0.y);       \
        mn[i][2] = fminf(mn[i][2], d0.z); mn[i][3] = fminf(mn[i][3], d0.w);       \
        mn[i][4] = fminf(mn[i][4], d1.x); mn[i][5] = fminf(mn[i][5], d1.y);       \
        mn[i][6] = fminf(mn[i][6], d1.z); mn[i][7] = fminf(mn[i][7], d1.w);       \
    } } while (0)

    float* buf0 = lds;
    float* buf1 = lds + 4096;

    if (wv == 1) WRITE_BLOB(buf0);
    if (wv == 3) WRITE_BLOB(buf1);
    __syncthreads();
    if (wv == 0) MERGE_BLOB(buf0);
    if (wv == 2) MERGE_BLOB(buf1);
    __syncthreads();
    if (wv == 2) WRITE_BLOB(buf0);
    __syncthreads();

    if (wv == 0) {
        MERGE_BLOB(buf0);
        // write this kc's partial plane (wave 0 only, 16 float4 stores/lane)
        const size_t plane = (size_t)B_TOK * N_OUT;
#pragma unroll
        for (int i = 0; i < 4; ++i) {
            const size_t o = (size_t)kc * plane
                           + (size_t)(b0 + bq * 4 + i) * N_OUT + n0 + nq * 8;
            *reinterpret_cast<float4*>(&pmx[o + 0]) =
                make_float4(mx[i][0], mx[i][1], mx[i][2], mx[i][3]);
            *reinterpret_cast<float4*>(&pmx[o + 4]) =
                make_float4(mx[i][4], mx[i][5], mx[i][6], mx[i][7]);
            *reinterpret_cast<float4*>(&pmn[o + 0]) =
                make_float4(mn[i][0], mn[i][1], mn[i][2], mn[i][3]);
            *reinterpret_cast<float4*>(&pmn[o + 4]) =
                make_float4(mn[i][4], mn[i][5], mn[i][6], mn[i][7]);
        }
    }
#undef BLOB_ST
#undef BLOB_LD
#undef WRITE_BLOB
#undef MERGE_BLOB
}

// ---------------- Stage 2: combine 8 planes + bias ----------------
__global__ __launch_bounds__(256)
void mam_stage2(const float* __restrict__ pmx, const float* __restrict__ pmn,
                const float* __restrict__ bias, float* __restrict__ out) {
    const size_t i4 = ((size_t)blockIdx.x * 256 + threadIdx.x) * 4;
    const size_t plane = (size_t)B_TOK * N_OUT;
    float4 MX = *reinterpret_cast<const float4*>(pmx + i4);
    float4 MN = *reinterpret_cast<const float4*>(pmn + i4);
#pragma unroll
    for (int p = 1; p < KSPLIT; ++p) {
        const float4 a = *reinterpret_cast<const float4*>(pmx + (size_t)p * plane + i4);
        const float4 d = *reinterpret_cast<const float4*>(pmn + (size_t)p * plane + i4);
        MX.x = fmaxf(MX.x, a.x); MX.y = fmaxf(MX.y, a.y);
        MX.z = fmaxf(MX.z, a.z); MX.w = fmaxf(MX.w, a.w);
        MN.x = fminf(MN.x, d.x); MN.y = fminf(MN.y, d.y);
        MN.z = fminf(MN.z, d.z); MN.w = fminf(MN.w, d.w);
    }
    const float4 bb = *reinterpret_cast<const float4*>(bias + (i4 & (N_OUT - 1)));
    float4 o;
    o.x = MX.x + MN.x + bb.x; o.y = MX.y + MN.y + bb.y;
    o.z = MX.z + MN.z + bb.z; o.w = MX.w + MN.w + bb.w;
    *reinterpret_cast<float4*>(out + i4) = o;
}

// ---------------- Fallback (workspace too small) ----------------
__global__ __launch_bounds__(256)
void mam_simple(const float* __restrict__ x, const float* __restrict__ w,
                const float* __restrict__ bias, float* __restrict__ out) {
    const int idx = blockIdx.x * 256 + threadIdx.x;
    const int b = idx / N_OUT, n = idx % N_OUT;
    const float* xr = x + (size_t)b * K_IN;
    const float* wr = w + (size_t)n * K_IN;
    float mx = -FLT_MAX, mn = FLT_MAX;
#pragma unroll 4
    for (int k = 0; k < K_IN; k += 4) {
        const float4 xv = *reinterpret_cast<const float4*>(xr + k);
        const float4 wv = *reinterpret_cast<const float4*>(wr + k);
        const float p0 = xv.x * wv.x, p1 = xv.y * wv.y;
        const float p2 = xv.z * wv.z, p3 = xv.w * wv.w;
        mx = fmaxf(fmaxf(mx, p0), p1);
        mx = fmaxf(fmaxf(mx, p2), p3);
        mn = fminf(fminf(mn, p0), p1);
        mn = fminf(fminf(mn, p2), p3);
    }
    out[idx] = mx + mn + bias[n];
}

extern "C" void kernel_launch(void* const* d_in, const int* in_sizes, int n_in,
                              void* d_out, int out_size, void* d_ws, size_t ws_size,
                              hipStream_t stream) {
    const float* x    = (const float*)d_in[0];   // [256,1024]
    const float* w    = (const float*)d_in[1];   // [512,1024]
    const float* bias = (const float*)d_in[2];   // [512]
    float* out = (float*)d_out;                  // [256,512] f32

    const size_t plane = (size_t)B_TOK * N_OUT;
    const size_t need  = 2 * (size_t)KSPLIT * plane * sizeof(float);  // 8 MB

    if (ws_size >= need) {
        float* pmx = (float*)d_ws;
        float* pmn = pmx + (size_t)KSPLIT * plane;
        mam_stage1<<<dim3(KSPLIT, N_OUT / NT, B_TOK / BT), 256, 0, stream>>>(x, w, pmx, pmn);
        mam_stage2<<<(int)(plane / 4 / 256), 256, 0, stream>>>(pmx, pmn, bias, out);
    } else {
        mam_simple<<<(B_TOK * N_OUT) / 256, 256, 0, stream>>>(x, w, bias, out);
    }
}